// Round 12
// baseline (148.997 us; speedup 1.0000x reference)
//
#include <hip/hip_runtime.h>

// RandomForest: 131072 samples x 64 feat, 64 trees depth 12, 8-class vote.
//
// R12 = R9 skeleton (SPB=256, TPB=1024, 4 slices x 16 trees, ILP=8 chains,
// 2 blocks/CU ~ 32 waves) + two latency/VALU cuts:
//  (1) h made wave-uniform via readfirstlane -> per-tree table bases are
//      SGPR-uniform -> saddr-form gathers, s_load for level-0 entry.
//  (2) per step, read x0/xL/xR in PARALLEL (addresses depend only on meta)
//      -> one LDS latency per step instead of two dependent ones.
// Series evidence: ILP=8 is load-bearing (R6/R11); MLP saturates ~128
// chains (R8~R9); LDS-table variants infeasible at ILP=8 + >=16 waves.

constexpr int kSamples  = 131072;
constexpr int kFeat     = 64;
constexpr int kTrees    = 64;
constexpr int kInternal = 4095;
constexpr int kClasses  = 8;

constexpr int TPB  = 1024;
constexpr int SPB  = 256;                        // samples per block
constexpr int XSTR = 256;                        // dwords; f column = f<<10 bytes
constexpr int XLDS_BYTES = kFeat * XSTR * 4;     // 65536 B
constexpr int ILP  = 8;
constexpr int TREES_PER_THREAD = 16;             // 4 thread-slices per sample

// Pair p covers levels 2p,2p+1; entries-before offsets {0,1,5,21,85}, 341/tree,
// stride 512 -> tree base = t<<9.
struct Pair  { float thr0, thrL, thrR; unsigned meta; };  // meta: f0|fL<<6|fR<<12
struct Sub16 { float thr10, thrL, thrR; unsigned meta; }; // +lv0..lv3 <<18,21,24,27

__global__ __launch_bounds__(256) void pack_pairs_kernel(
    const int* __restrict__ features, const float* __restrict__ thresholds,
    Pair* __restrict__ pairsA)
{
    int i = blockIdx.x * 256 + threadIdx.x;       // over 64*341
    if (i >= kTrees * 341) return;
    int t = i / 341;
    int e = i - t * 341;
    int p, m;
    if      (e < 1)  { p = 0; m = e; }
    else if (e < 5)  { p = 1; m = e - 1; }
    else if (e < 21) { p = 2; m = e - 5; }
    else if (e < 85) { p = 3; m = e - 21; }
    else             { p = 4; m = e - 85; }
    int g0 = (1 << (2 * p)) - 1 + m;              // global node id at level 2p
    int b  = t * kInternal;
    Pair pr;
    pr.thr0 = thresholds[b + g0];
    pr.thrL = thresholds[b + 2 * g0 + 1];
    pr.thrR = thresholds[b + 2 * g0 + 2];
    pr.meta = (unsigned)features[b + g0]
            | ((unsigned)features[b + 2 * g0 + 1] << 6)
            | ((unsigned)features[b + 2 * g0 + 2] << 12);
    pairsA[(t << 9) + e] = pr;
}

__global__ __launch_bounds__(256) void pack_sub_kernel(
    const int* __restrict__ features, const float* __restrict__ thresholds,
    const int* __restrict__ leaf_values, Sub16* __restrict__ subsA)
{
    int i = blockIdx.x * 256 + threadIdx.x;       // over 64*1024
    if (i >= kTrees * 1024) return;
    int t = i >> 10;
    int j = i & 1023;                              // level-10 local index
    int n10 = 1023 + j;
    int b   = t * kInternal;
    Sub16 sb;
    sb.thr10 = thresholds[b + n10];
    sb.thrL  = thresholds[b + 2 * n10 + 1];
    sb.thrR  = thresholds[b + 2 * n10 + 2];
    const int* lv = leaf_values + ((t << 12) + 4 * j);
    sb.meta = (unsigned)features[b + n10]
            | ((unsigned)features[b + 2 * n10 + 1] << 6)
            | ((unsigned)features[b + 2 * n10 + 2] << 12)
            | ((unsigned)lv[0] << 18) | ((unsigned)lv[1] << 21)
            | ((unsigned)lv[2] << 24) | ((unsigned)lv[3] << 27);
    subsA[(t << 10) + j] = sb;
}

// One pair step: read x0/xL/xR in parallel (addresses from meta only),
// one LDS-latency chain per step.
__device__ __forceinline__ int step_pair(const Pair& pr, const char* __restrict__ xb,
                                         int m)
{
    unsigned mt = pr.meta;
    float x0 = *(const float*)(xb + ((mt & 63u) << 10));
    float xL = *(const float*)(xb + (((mt >> 6) & 63u) << 10));
    float xR = *(const float*)(xb + (((mt >> 12) & 63u) << 10));
    int   c0 = x0 > pr.thr0 ? 1 : 0;
    float t1 = c0 ? pr.thrR : pr.thrL;
    float x1 = c0 ? xR : xL;
    int   c1 = x1 > t1 ? 1 : 0;
    return 4 * m + 2 * c0 + c1;
}

__global__ __launch_bounds__(TPB, 8) void forest_kernel(
    const float* __restrict__ X,
    const Pair*  __restrict__ pairsA,   // [64][512] (341 used)
    const Sub16* __restrict__ subsA,    // [64][1024]
    int* __restrict__ out)
{
    extern __shared__ float xs[];                  // [64][256] feature-major
    const int tid  = threadIdx.x;
    const int s    = tid & (SPB - 1);              // sample slot 0..255
    // tid>>8 is uniform across each 64-lane wave (256 % 64 == 0); making it
    // provably uniform turns all per-tree bases into SGPRs (saddr gathers).
    const int h    = __builtin_amdgcn_readfirstlane(tid >> 8);  // slice 0..3
    const int base = blockIdx.x * SPB;

    // Stage: 4 threads per sample each load a quarter-row (4 float4).
    // LDS writes at f*256+s -> bank = s%32, consecutive lanes = 2-way (free).
    {
        const float4* Xr = (const float4*)(X + (size_t)(base + s) * kFeat) + h * 4;
        #pragma unroll
        for (int k = 0; k < 4; ++k) {
            float4 v = Xr[k];
            int f0 = (h * 4 + k) * 4;
            xs[(f0 + 0) * XSTR + s] = v.x;
            xs[(f0 + 1) * XSTR + s] = v.y;
            xs[(f0 + 2) * XSTR + s] = v.z;
            xs[(f0 + 3) * XSTR + s] = v.w;
        }
    }
    __syncthreads();

    const char* xb = (const char*)xs + (s << 2);   // + (f<<10) per access
    unsigned long long votes = 0ull;

    const int mofs[4] = {0, 1, 5, 21};             // shallow pair offsets

    const int tbeg = h * TREES_PER_THREAD;
    for (int t0 = tbeg; t0 < tbeg + TREES_PER_THREAD; t0 += ILP) {
        int m[ILP];
        #pragma unroll
        for (int j = 0; j < ILP; ++j) m[j] = 0;

        #pragma unroll
        for (int p = 0; p < 4; ++p) {              // levels 0..7
            #pragma unroll
            for (int j = 0; j < ILP; ++j) {        // 8 independent chains
                const Pair* tp = pairsA + ((t0 + j) << 9);   // uniform base
                m[j] = step_pair(tp[mofs[p] + m[j]], xb, m[j]);
            }
        }

        #pragma unroll
        for (int j = 0; j < ILP; ++j) {            // levels 8,9 (pair4)
            const Pair* tp = pairsA + ((t0 + j) << 9) + 85;  // uniform base
            m[j] = step_pair(tp[m[j]], xb, m[j]);
        }

        #pragma unroll
        for (int j = 0; j < ILP; ++j) {            // levels 10,11 + leaf
            const Sub16* sp = subsA + ((t0 + j) << 10);      // uniform base
            Sub16 sb = sp[m[j]];
            unsigned mt = sb.meta;
            float x0 = *(const float*)(xb + ((mt & 63u) << 10));
            float xL = *(const float*)(xb + (((mt >> 6) & 63u) << 10));
            float xR = *(const float*)(xb + (((mt >> 12) & 63u) << 10));
            int   c0 = x0 > sb.thr10 ? 1 : 0;
            float t1 = c0 ? sb.thrR : sb.thrL;
            float x1 = c0 ? xR : xL;
            int   c1 = x1 > t1 ? 1 : 0;
            int cls = (mt >> (18 + 3 * ((c0 << 1) | c1))) & 7;
            votes += 1ull << (cls << 3);
        }
    }

    // Combine 4 partial vote vectors per sample through LDS (xs dead now).
    __syncthreads();
    unsigned long long* vbuf = (unsigned long long*)xs;   // 3*256 u64 = 6 KiB
    if (h != 0) vbuf[(h - 1) * SPB + s] = votes;
    __syncthreads();
    if (h == 0) {
        votes += vbuf[s] + vbuf[SPB + s] + vbuf[2 * SPB + s];
        // argmax over 8 packed byte counters; strict '>' keeps smallest class
        int best = 0;
        int bc   = (int)(votes & 0xFFull);
        #pragma unroll
        for (int c = 1; c < kClasses; ++c) {
            int cnt = (int)((votes >> (c * 8)) & 0xFFull);
            if (cnt > bc) { bc = cnt; best = c; }
        }
        out[base + s] = best;
    }
}

extern "C" void kernel_launch(void* const* d_in, const int* in_sizes, int n_in,
                              void* d_out, int out_size, void* d_ws, size_t ws_size,
                              hipStream_t stream) {
    const float* X          = (const float*)d_in[0];
    const int*   features   = (const int*)d_in[1];
    const float* thresholds = (const float*)d_in[2];
    const int*   leaves     = (const int*)d_in[3];
    int*         out        = (int*)d_out;

    Pair*  pairsA = (Pair*)d_ws;                            // 64*512*16 = 512 KiB
    Sub16* subsA  = (Sub16*)((char*)d_ws + (kTrees << 13)); // +512 KiB, 1 MiB

    (void)hipFuncSetAttribute((const void*)forest_kernel,
                              hipFuncAttributeMaxDynamicSharedMemorySize,
                              XLDS_BYTES);

    pack_pairs_kernel<<<(kTrees * 341 + 255) / 256, 256, 0, stream>>>(
        features, thresholds, pairsA);
    pack_sub_kernel<<<(kTrees * 1024 + 255) / 256, 256, 0, stream>>>(
        features, thresholds, leaves, subsA);
    forest_kernel<<<kSamples / SPB, TPB, XLDS_BYTES, stream>>>(
        X, pairsA, subsA, out);
}

// Round 13
// 131.383 us; speedup vs baseline: 1.1341x; 1.1341x over previous
//
#include <hip/hip_runtime.h>

// RandomForest: 131072 samples x 64 feat, 64 trees depth 12, 8-class vote.
//
// R13 = exact R9 revert (best: 47.2us) + ONE isolated change: the Sub16
// gather (levels 10,11+leaves; 16KiB/tree, can never be L1-resident at
// this tree diversity) is nontemporal -> no L1 allocation, so the smaller
// pair tables keep their partial L1 residency.
// R12 lessons: 3-parallel-X-reads and readfirstlane/scalar-base addressing
// both REGRESS (occupancy up, VALUBusy down, +70% time) - reverted.
// Series: ILP=8 load-bearing (R6,R11); TLP saturated (R8~R9); plateau is
// multi-pipe (L2 random-line ~21-27 TB/s + VALU ~45% + LDS ~30%).

constexpr int kSamples  = 131072;
constexpr int kFeat     = 64;
constexpr int kTrees    = 64;
constexpr int kInternal = 4095;
constexpr int kClasses  = 8;

constexpr int TPB  = 1024;
constexpr int SPB  = 256;                        // samples per block
constexpr int XSTR = 256;                        // dwords; f column = f<<10 bytes
constexpr int XLDS_BYTES = kFeat * XSTR * 4;     // 65536 B
constexpr int ILP  = 8;
constexpr int TREES_PER_THREAD = 16;             // 4 thread-slices per sample

typedef unsigned int u32x4 __attribute__((ext_vector_type(4)));  // nt-load-able

// Pair p covers levels 2p,2p+1; entries-before offsets {0,1,5,21,85}, 341/tree,
// stride 512 -> tree base = t<<9.
struct Pair  { float thr0, thrL, thrR; unsigned meta; };  // meta: f0|fL<<6|fR<<12
struct Sub16 { float thr10, thrL, thrR; unsigned meta; }; // +lv0..lv3 <<18,21,24,27

__global__ __launch_bounds__(256) void pack_pairs_kernel(
    const int* __restrict__ features, const float* __restrict__ thresholds,
    Pair* __restrict__ pairsA)
{
    int i = blockIdx.x * 256 + threadIdx.x;       // over 64*341
    if (i >= kTrees * 341) return;
    int t = i / 341;
    int e = i - t * 341;
    int p, m;
    if      (e < 1)  { p = 0; m = e; }
    else if (e < 5)  { p = 1; m = e - 1; }
    else if (e < 21) { p = 2; m = e - 5; }
    else if (e < 85) { p = 3; m = e - 21; }
    else             { p = 4; m = e - 85; }
    int g0 = (1 << (2 * p)) - 1 + m;              // global node id at level 2p
    int b  = t * kInternal;
    Pair pr;
    pr.thr0 = thresholds[b + g0];
    pr.thrL = thresholds[b + 2 * g0 + 1];
    pr.thrR = thresholds[b + 2 * g0 + 2];
    pr.meta = (unsigned)features[b + g0]
            | ((unsigned)features[b + 2 * g0 + 1] << 6)
            | ((unsigned)features[b + 2 * g0 + 2] << 12);
    pairsA[(t << 9) + e] = pr;
}

__global__ __launch_bounds__(256) void pack_sub_kernel(
    const int* __restrict__ features, const float* __restrict__ thresholds,
    const int* __restrict__ leaf_values, Sub16* __restrict__ subsA)
{
    int i = blockIdx.x * 256 + threadIdx.x;       // over 64*1024
    if (i >= kTrees * 1024) return;
    int t = i >> 10;
    int j = i & 1023;                              // level-10 local index
    int n10 = 1023 + j;
    int b   = t * kInternal;
    Sub16 sb;
    sb.thr10 = thresholds[b + n10];
    sb.thrL  = thresholds[b + 2 * n10 + 1];
    sb.thrR  = thresholds[b + 2 * n10 + 2];
    const int* lv = leaf_values + ((t << 12) + 4 * j);
    sb.meta = (unsigned)features[b + n10]
            | ((unsigned)features[b + 2 * n10 + 1] << 6)
            | ((unsigned)features[b + 2 * n10 + 2] << 12)
            | ((unsigned)lv[0] << 18) | ((unsigned)lv[1] << 21)
            | ((unsigned)lv[2] << 24) | ((unsigned)lv[3] << 27);
    subsA[(t << 10) + j] = sb;
}

__global__ __launch_bounds__(TPB, 8) void forest_kernel(
    const float* __restrict__ X,
    const Pair*  __restrict__ pairsA,   // [64][512] (341 used)
    const Sub16* __restrict__ subsA,    // [64][1024]
    int* __restrict__ out)
{
    extern __shared__ float xs[];                  // [64][256] feature-major
    const int tid  = threadIdx.x;
    const int s    = tid & (SPB - 1);              // sample slot 0..255
    const int h    = tid >> 8;                     // forest quarter 0..3
    const int base = blockIdx.x * SPB;

    // Stage: 4 threads per sample each load a quarter-row (4 float4).
    // LDS writes at f*256+s -> bank = s%32, consecutive lanes = 2-way (free).
    {
        const float4* Xr = (const float4*)(X + (size_t)(base + s) * kFeat) + h * 4;
        #pragma unroll
        for (int k = 0; k < 4; ++k) {
            float4 v = Xr[k];
            int f0 = (h * 4 + k) * 4;
            xs[(f0 + 0) * XSTR + s] = v.x;
            xs[(f0 + 1) * XSTR + s] = v.y;
            xs[(f0 + 2) * XSTR + s] = v.z;
            xs[(f0 + 3) * XSTR + s] = v.w;
        }
    }
    __syncthreads();

    const char* xb = (const char*)xs + (s << 2);   // + (f<<10) per access
    unsigned long long votes = 0ull;

    const int mofs[4] = {0, 1, 5, 21};             // shallow pair offsets

    const int tbeg = h * TREES_PER_THREAD;
    for (int t0 = tbeg; t0 < tbeg + TREES_PER_THREAD; t0 += ILP) {
        int m[ILP];
        #pragma unroll
        for (int j = 0; j < ILP; ++j) m[j] = 0;

        #pragma unroll
        for (int p = 0; p < 4; ++p) {              // levels 0..7
            #pragma unroll
            for (int j = 0; j < ILP; ++j) {        // 8 independent chains
                Pair pr = pairsA[((t0 + j) << 9) + mofs[p] + m[j]];
                float x0 = *(const float*)(xb + ((pr.meta & 63u) << 10));
                int c0 = x0 > pr.thr0 ? 1 : 0;
                float thr1     = c0 ? pr.thrR : pr.thrL;
                unsigned fsel  = c0 ? (pr.meta >> 12) : (pr.meta >> 6);
                float x1 = *(const float*)(xb + ((fsel & 63u) << 10));
                int c1 = x1 > thr1 ? 1 : 0;
                m[j] = 4 * m[j] + 2 * c0 + c1;
            }
        }

        #pragma unroll
        for (int j = 0; j < ILP; ++j) {            // levels 8,9 (pair4)
            Pair pr = pairsA[((t0 + j) << 9) + 85 + m[j]];
            float x0 = *(const float*)(xb + ((pr.meta & 63u) << 10));
            int c0 = x0 > pr.thr0 ? 1 : 0;
            float thr1     = c0 ? pr.thrR : pr.thrL;
            unsigned fsel  = c0 ? (pr.meta >> 12) : (pr.meta >> 6);
            float x1 = *(const float*)(xb + ((fsel & 63u) << 10));
            int c1 = x1 > thr1 ? 1 : 0;
            m[j] = 4 * m[j] + 2 * c0 + c1;
        }

        #pragma unroll
        for (int j = 0; j < ILP; ++j) {            // levels 10,11 + leaf: NT load
            const u32x4* sp = (const u32x4*)(subsA + ((t0 + j) << 10) + m[j]);
            u32x4 v = __builtin_nontemporal_load(sp);   // no L1 alloc
            float thr10 = __uint_as_float(v.x);
            float thrL  = __uint_as_float(v.y);
            float thrR  = __uint_as_float(v.z);
            unsigned mt = v.w;
            float x0 = *(const float*)(xb + ((mt & 63u) << 10));
            int c0 = x0 > thr10 ? 1 : 0;
            float thr1    = c0 ? thrR : thrL;
            unsigned fsel = c0 ? (mt >> 12) : (mt >> 6);
            float x1 = *(const float*)(xb + ((fsel & 63u) << 10));
            int c1 = x1 > thr1 ? 1 : 0;
            int cls = (mt >> (18 + 3 * ((c0 << 1) | c1))) & 7;
            votes += 1ull << (cls << 3);
        }
    }

    // Combine 4 partial vote vectors per sample through LDS (xs dead now).
    __syncthreads();
    unsigned long long* vbuf = (unsigned long long*)xs;   // 3*256 u64 = 6 KiB
    if (h != 0) vbuf[(h - 1) * SPB + s] = votes;
    __syncthreads();
    if (h == 0) {
        votes += vbuf[s] + vbuf[SPB + s] + vbuf[2 * SPB + s];
        // argmax over 8 packed byte counters; strict '>' keeps smallest class
        int best = 0;
        int bc   = (int)(votes & 0xFFull);
        #pragma unroll
        for (int c = 1; c < kClasses; ++c) {
            int cnt = (int)((votes >> (c * 8)) & 0xFFull);
            if (cnt > bc) { bc = cnt; best = c; }
        }
        out[base + s] = best;
    }
}

extern "C" void kernel_launch(void* const* d_in, const int* in_sizes, int n_in,
                              void* d_out, int out_size, void* d_ws, size_t ws_size,
                              hipStream_t stream) {
    const float* X          = (const float*)d_in[0];
    const int*   features   = (const int*)d_in[1];
    const float* thresholds = (const float*)d_in[2];
    const int*   leaves     = (const int*)d_in[3];
    int*         out        = (int*)d_out;

    Pair*  pairsA = (Pair*)d_ws;                            // 64*512*16 = 512 KiB
    Sub16* subsA  = (Sub16*)((char*)d_ws + (kTrees << 13)); // +512 KiB, 1 MiB

    (void)hipFuncSetAttribute((const void*)forest_kernel,
                              hipFuncAttributeMaxDynamicSharedMemorySize,
                              XLDS_BYTES);

    pack_pairs_kernel<<<(kTrees * 341 + 255) / 256, 256, 0, stream>>>(
        features, thresholds, pairsA);
    pack_sub_kernel<<<(kTrees * 1024 + 255) / 256, 256, 0, stream>>>(
        features, thresholds, leaves, subsA);
    forest_kernel<<<kSamples / SPB, TPB, XLDS_BYTES, stream>>>(
        X, pairsA, subsA, out);
}

// Round 14
// 118.092 us; speedup vs baseline: 1.2617x; 1.1126x over previous
//
#include <hip/hip_runtime.h>

// RandomForest: 131072 samples x 64 feat, 64 trees depth 12, 8-class vote.
//
// R14 = exact revert to R9 (best of series: 47.2us).
// Structure: pairs (2 levels per 16B entry, one dwordx4 gather resolves 2
// levels) for lvls 0..9 + Sub16 (lvls 10,11 + 4 leaf classes) -> 6 gathers
// per walk. X feature-major in LDS (bank = s%32, f-independent, conflict-
// free). SPB=256, TPB=1024, 4 slices x 16 trees, ILP=8 chains, 2 blocks/CU
// = 32 waves/CU (hardware cap).
// Series post-mortems: ILP=8 load-bearing (R6,R11 regress at ILP<=4);
// TLP saturated (R8->R9 neutral); L1-residency windows regress (R11);
// LDS tree tables capacity-infeasible at ILP=8 (R6, re-derived); nt-loads
// demote L2 residency and regress (R13, FETCH_SIZE +3.2MB); scalar-base /
// parallel-X-read step regress (R12). Plateau: ~1.0 GB/launch of random
// 64B L2->L1 line fills (~21 TB/s) + VALU ~45% + LDS ~30%, all unsaturated
// individually but jointly binding.

constexpr int kSamples  = 131072;
constexpr int kFeat     = 64;
constexpr int kTrees    = 64;
constexpr int kInternal = 4095;
constexpr int kClasses  = 8;

constexpr int TPB  = 1024;
constexpr int SPB  = 256;                        // samples per block
constexpr int XSTR = 256;                        // dwords; f column = f<<10 bytes
constexpr int XLDS_BYTES = kFeat * XSTR * 4;     // 65536 B
constexpr int ILP  = 8;
constexpr int TREES_PER_THREAD = 16;             // 4 thread-slices per sample

// Pair p covers levels 2p,2p+1; entries-before offsets {0,1,5,21,85}, 341/tree,
// stride 512 -> tree base = t<<9.
struct Pair  { float thr0, thrL, thrR; unsigned meta; };  // meta: f0|fL<<6|fR<<12
struct Sub16 { float thr10, thrL, thrR; unsigned meta; }; // +lv0..lv3 <<18,21,24,27

__global__ __launch_bounds__(256) void pack_pairs_kernel(
    const int* __restrict__ features, const float* __restrict__ thresholds,
    Pair* __restrict__ pairsA)
{
    int i = blockIdx.x * 256 + threadIdx.x;       // over 64*341
    if (i >= kTrees * 341) return;
    int t = i / 341;
    int e = i - t * 341;
    int p, m;
    if      (e < 1)  { p = 0; m = e; }
    else if (e < 5)  { p = 1; m = e - 1; }
    else if (e < 21) { p = 2; m = e - 5; }
    else if (e < 85) { p = 3; m = e - 21; }
    else             { p = 4; m = e - 85; }
    int g0 = (1 << (2 * p)) - 1 + m;              // global node id at level 2p
    int b  = t * kInternal;
    Pair pr;
    pr.thr0 = thresholds[b + g0];
    pr.thrL = thresholds[b + 2 * g0 + 1];
    pr.thrR = thresholds[b + 2 * g0 + 2];
    pr.meta = (unsigned)features[b + g0]
            | ((unsigned)features[b + 2 * g0 + 1] << 6)
            | ((unsigned)features[b + 2 * g0 + 2] << 12);
    pairsA[(t << 9) + e] = pr;
}

__global__ __launch_bounds__(256) void pack_sub_kernel(
    const int* __restrict__ features, const float* __restrict__ thresholds,
    const int* __restrict__ leaf_values, Sub16* __restrict__ subsA)
{
    int i = blockIdx.x * 256 + threadIdx.x;       // over 64*1024
    if (i >= kTrees * 1024) return;
    int t = i >> 10;
    int j = i & 1023;                              // level-10 local index
    int n10 = 1023 + j;
    int b   = t * kInternal;
    Sub16 sb;
    sb.thr10 = thresholds[b + n10];
    sb.thrL  = thresholds[b + 2 * n10 + 1];
    sb.thrR  = thresholds[b + 2 * n10 + 2];
    const int* lv = leaf_values + ((t << 12) + 4 * j);
    sb.meta = (unsigned)features[b + n10]
            | ((unsigned)features[b + 2 * n10 + 1] << 6)
            | ((unsigned)features[b + 2 * n10 + 2] << 12)
            | ((unsigned)lv[0] << 18) | ((unsigned)lv[1] << 21)
            | ((unsigned)lv[2] << 24) | ((unsigned)lv[3] << 27);
    subsA[(t << 10) + j] = sb;
}

__global__ __launch_bounds__(TPB, 8) void forest_kernel(
    const float* __restrict__ X,
    const Pair*  __restrict__ pairsA,   // [64][512] (341 used)
    const Sub16* __restrict__ subsA,    // [64][1024]
    int* __restrict__ out)
{
    extern __shared__ float xs[];                  // [64][256] feature-major
    const int tid  = threadIdx.x;
    const int s    = tid & (SPB - 1);              // sample slot 0..255
    const int h    = tid >> 8;                     // forest quarter 0..3
    const int base = blockIdx.x * SPB;

    // Stage: 4 threads per sample each load a quarter-row (4 float4).
    // LDS writes at f*256+s -> bank = s%32, consecutive lanes = 2-way (free).
    {
        const float4* Xr = (const float4*)(X + (size_t)(base + s) * kFeat) + h * 4;
        #pragma unroll
        for (int k = 0; k < 4; ++k) {
            float4 v = Xr[k];
            int f0 = (h * 4 + k) * 4;
            xs[(f0 + 0) * XSTR + s] = v.x;
            xs[(f0 + 1) * XSTR + s] = v.y;
            xs[(f0 + 2) * XSTR + s] = v.z;
            xs[(f0 + 3) * XSTR + s] = v.w;
        }
    }
    __syncthreads();

    const char* xb = (const char*)xs + (s << 2);   // + (f<<10) per access
    unsigned long long votes = 0ull;

    const int mofs[4] = {0, 1, 5, 21};             // shallow pair offsets

    const int tbeg = h * TREES_PER_THREAD;
    for (int t0 = tbeg; t0 < tbeg + TREES_PER_THREAD; t0 += ILP) {
        int m[ILP];
        #pragma unroll
        for (int j = 0; j < ILP; ++j) m[j] = 0;

        #pragma unroll
        for (int p = 0; p < 4; ++p) {              // levels 0..7
            #pragma unroll
            for (int j = 0; j < ILP; ++j) {        // 8 independent chains
                Pair pr = pairsA[((t0 + j) << 9) + mofs[p] + m[j]];
                float x0 = *(const float*)(xb + ((pr.meta & 63u) << 10));
                int c0 = x0 > pr.thr0 ? 1 : 0;
                float thr1     = c0 ? pr.thrR : pr.thrL;
                unsigned fsel  = c0 ? (pr.meta >> 12) : (pr.meta >> 6);
                float x1 = *(const float*)(xb + ((fsel & 63u) << 10));
                int c1 = x1 > thr1 ? 1 : 0;
                m[j] = 4 * m[j] + 2 * c0 + c1;
            }
        }

        #pragma unroll
        for (int j = 0; j < ILP; ++j) {            // levels 8,9 (pair4)
            Pair pr = pairsA[((t0 + j) << 9) + 85 + m[j]];
            float x0 = *(const float*)(xb + ((pr.meta & 63u) << 10));
            int c0 = x0 > pr.thr0 ? 1 : 0;
            float thr1     = c0 ? pr.thrR : pr.thrL;
            unsigned fsel  = c0 ? (pr.meta >> 12) : (pr.meta >> 6);
            float x1 = *(const float*)(xb + ((fsel & 63u) << 10));
            int c1 = x1 > thr1 ? 1 : 0;
            m[j] = 4 * m[j] + 2 * c0 + c1;
        }

        #pragma unroll
        for (int j = 0; j < ILP; ++j) {            // levels 10,11 + leaf
            Sub16 sb = subsA[((t0 + j) << 10) + m[j]];
            unsigned mt = sb.meta;
            float x0 = *(const float*)(xb + ((mt & 63u) << 10));
            int c0 = x0 > sb.thr10 ? 1 : 0;
            float thr1    = c0 ? sb.thrR : sb.thrL;
            unsigned fsel = c0 ? (mt >> 12) : (mt >> 6);
            float x1 = *(const float*)(xb + ((fsel & 63u) << 10));
            int c1 = x1 > thr1 ? 1 : 0;
            int cls = (mt >> (18 + 3 * ((c0 << 1) | c1))) & 7;
            votes += 1ull << (cls << 3);
        }
    }

    // Combine 4 partial vote vectors per sample through LDS (xs dead now).
    __syncthreads();
    unsigned long long* vbuf = (unsigned long long*)xs;   // 3*256 u64 = 6 KiB
    if (h != 0) vbuf[(h - 1) * SPB + s] = votes;
    __syncthreads();
    if (h == 0) {
        votes += vbuf[s] + vbuf[SPB + s] + vbuf[2 * SPB + s];
        // argmax over 8 packed byte counters; strict '>' keeps smallest class
        int best = 0;
        int bc   = (int)(votes & 0xFFull);
        #pragma unroll
        for (int c = 1; c < kClasses; ++c) {
            int cnt = (int)((votes >> (c * 8)) & 0xFFull);
            if (cnt > bc) { bc = cnt; best = c; }
        }
        out[base + s] = best;
    }
}

extern "C" void kernel_launch(void* const* d_in, const int* in_sizes, int n_in,
                              void* d_out, int out_size, void* d_ws, size_t ws_size,
                              hipStream_t stream) {
    const float* X          = (const float*)d_in[0];
    const int*   features   = (const int*)d_in[1];
    const float* thresholds = (const float*)d_in[2];
    const int*   leaves     = (const int*)d_in[3];
    int*         out        = (int*)d_out;

    Pair*  pairsA = (Pair*)d_ws;                            // 64*512*16 = 512 KiB
    Sub16* subsA  = (Sub16*)((char*)d_ws + (kTrees << 13)); // +512 KiB, 1 MiB

    (void)hipFuncSetAttribute((const void*)forest_kernel,
                              hipFuncAttributeMaxDynamicSharedMemorySize,
                              XLDS_BYTES);

    pack_pairs_kernel<<<(kTrees * 341 + 255) / 256, 256, 0, stream>>>(
        features, thresholds, pairsA);
    pack_sub_kernel<<<(kTrees * 1024 + 255) / 256, 256, 0, stream>>>(
        features, thresholds, leaves, subsA);
    forest_kernel<<<kSamples / SPB, TPB, XLDS_BYTES, stream>>>(
        X, pairsA, subsA, out);
}